// Round 4
// baseline (234.790 us; speedup 1.0000x reference)
//
#include <hip/hip_runtime.h>
#include <hip/hip_bf16.h>
#include <cstdint>
#include <cstddef>

// Problem constants
constexpr int T = 8;
constexpr int C = 256;     // feature channels = GEMM K
constexpr int N = 4096;    // H*W pixels per frame
constexpr float TEMP_INV = 14.285714285714286f;  // 1/0.07
constexpr float EPS = 1e-8f;

typedef __bf16 bf16;
typedef __bf16 bf16x8 __attribute__((ext_vector_type(8)));
typedef float floatx16 __attribute__((ext_vector_type(16)));

// ---------------------------------------------------------------------------
// Fused per-frame dice stats + labels + negbuf zero + fg/bg compaction.
// Grid: 8 blocks (one per frame) x 1024 threads (16 waves).
__global__ void prep_kernel(const float* __restrict__ cur,
                            const float* __restrict__ hist,
                            float* __restrict__ out_labels,
                            float* __restrict__ negbuf,
                            unsigned short* __restrict__ fgidx,
                            unsigned short* __restrict__ bgidx,
                            int* __restrict__ nfg, int* __restrict__ nbg) {
    int t = blockIdx.x;
    int tid = threadIdx.x;
    int lane = tid & 63;
    int w = tid >> 6;

    float cv[4], hv[4];
    float s1 = 0.f, sc = 0.f, sh = 0.f;
    for (int it = 0; it < 4; ++it) {
        int p = it * 1024 + tid;
        float c = cur[t * N + p];
        float h = hist[t * N + p];
        cv[it] = c; hv[it] = h;
        float cb = c > 0.5f ? 1.f : 0.f;
        float hb = h > 0.5f ? 1.f : 0.f;
        s1 += cb * hb; sc += cb; sh += hb;
    }
    for (int o = 32; o > 0; o >>= 1) {
        s1 += __shfl_down(s1, o);
        sc += __shfl_down(sc, o);
        sh += __shfl_down(sh, o);
    }
    __shared__ float r1[16], r2[16], r3[16];
    __shared__ float uflag;
    __shared__ int cfg_s, cbg_s;
    if (lane == 0) { r1[w] = s1; r2[w] = sc; r3[w] = sh; }
    if (tid == 0) { cfg_s = 0; cbg_s = 0; }
    __syncthreads();
    if (tid == 0) {
        float e1 = 0.f, scs = 0.f, shs = 0.f;
        for (int i = 0; i < 16; ++i) { e1 += r1[i]; scs += r2[i]; shs += r3[i]; }
        float e2 = scs + shs;
        float m1 = (2.f * e1 + EPS) / (e2 + EPS);
        float m2 = (e1 + EPS) / (e2 - e1 + EPS);
        float dev = 1.f - 0.5f * (m1 + m2);
        uflag = (dev <= 0.0f) ? 1.f : 0.f;
    }
    __syncthreads();
    bool use_curr = uflag != 0.f;
    for (int it = 0; it < 4; ++it) {
        int p = it * 1024 + tid;
        int gi = t * N + p;
        float lab = use_curr ? cv[it] : hv[it];
        out_labels[gi] = lab;
        negbuf[gi] = 0.f;
        bool fg = lab > 0.5f;
        unsigned long long b = __ballot(fg);
        unsigned long long lowmask = (lane == 63) ? 0x7fffffffffffffffull
                                                  : ((1ull << lane) - 1ull);
        int rank_fg = __popcll(b & lowmask);
        int rank_bg = __popcll((~b) & lowmask);
        int cnt_fg = __popcll(b);
        int base_fg = 0, base_bg = 0;
        if (lane == 0) {
            base_fg = atomicAdd(&cfg_s, cnt_fg);
            base_bg = atomicAdd(&cbg_s, 64 - cnt_fg);
        }
        base_fg = __shfl(base_fg, 0);
        base_bg = __shfl(base_bg, 0);
        if (fg) fgidx[t * N + base_fg + rank_fg] = (unsigned short)p;
        else    bgidx[t * N + base_bg + rank_bg] = (unsigned short)p;
    }
    __syncthreads();
    if (tid == 0) { nfg[t] = cfg_s; nbg[t] = cbg_s; }
}

// ---------------------------------------------------------------------------
// Normalize features, transpose [T][C][N] -> bf16 [T][N][C], posdot = ||fhat||^2.
__global__ __launch_bounds__(256) void normalize_kernel(const float* __restrict__ feat,
                                                        bf16* __restrict__ fhat,
                                                        float* __restrict__ posdot) {
    __shared__ bf16 tile[64 * 258];    // [n][c], pad 258 (bf16)
    __shared__ float partial[256];
    __shared__ float rnorm_s[64];
    int t = blockIdx.x >> 6;           // 8 frames
    int n0 = (blockIdx.x & 63) * 64;   // 64 pixel rows per block
    int tid = threadIdx.x;
    int lane63 = tid & 63;             // pixel within tile
    int w = tid >> 6;                  // wave -> 64-channel slab
    const float* fb = feat + (size_t)t * C * N;
    float ss = 0.f;
    for (int it = 0; it < 64; ++it) {
        int c = w * 64 + it;
        float v = fb[(size_t)c * N + n0 + lane63];
        ss += v * v;
        tile[lane63 * 258 + c] = (bf16)v;
    }
    partial[tid] = ss;
    __syncthreads();
    if (tid < 64) {
        float s = partial[tid] + partial[tid + 64] + partial[tid + 128] + partial[tid + 192];
        float r = 1.f / fmaxf(sqrtf(s), 1e-12f);
        rnorm_s[tid] = r;
        posdot[t * N + n0 + tid] = s * r * r;
    }
    __syncthreads();
    bf16* ob = fhat + ((size_t)t * N + n0) * C;
    for (int it = 0; it < 8; ++it) {
        int l = it * 256 + tid;        // short8 index, 0..2047
        int n = l >> 5;
        int c = (l & 31) * 8;
        float r = rnorm_s[n];
        bf16x8 vin = *(const bf16x8*)&tile[n * 258 + c];
        bf16x8 vo;
        for (int j = 0; j < 8; ++j) vo[j] = (bf16)((float)vin[j] * r);
        *(bf16x8*)(ob + l * 8) = vo;
    }
}

// ---------------------------------------------------------------------------
// sim GEMM + exp + bg row-sum: single-wave workgroups, NO LDS, NO BARRIERS.
// Each wave computes a 64(fg rows) x 128(bg cols) tile as 2x4 mfma_32x32x16
// accumulators; A/B fragments gathered straight from global into VGPRs with a
// distance-2 register prefetch pipeline. Grid: 16384 virtual tiles; inactive
// tiles exit immediately.
__global__ __launch_bounds__(64, 2) void sim_kernel(const bf16* __restrict__ fhat,
                                                    const unsigned short* __restrict__ fgidx,
                                                    const unsigned short* __restrict__ bgidx,
                                                    const int* __restrict__ nfg,
                                                    const int* __restrict__ nbg,
                                                    float* __restrict__ neg) {
    int vt = blockIdx.x;
    int t = vt >> 11;                  // 2048 virtual tiles per frame
    int rem = vt & 2047;
    int rowbase = (rem >> 5) * 64;     // 64 virtual row tiles
    int colbase = (rem & 31) * 128;    // 32 virtual col tiles
    int nfgt = nfg[t];
    int nbgt = nbg[t];
    if (rowbase >= nfgt || colbase >= nbgt) return;

    int lane = threadIdx.x;
    int l31 = lane & 31;
    int koff = (lane >> 5) * 8;        // fragment K-offset for this half-wave
    const bf16* fb = fhat + (size_t)t * N * C;

    const bf16* ap[2];
    const bf16* bp[4];
    for (int i = 0; i < 2; ++i) {
        int ra = rowbase + i * 32 + l31; if (ra >= nfgt) ra = nfgt - 1;
        ap[i] = fb + (size_t)fgidx[t * N + ra] * C + koff;
    }
    for (int j = 0; j < 4; ++j) {
        int cc = colbase + j * 32 + l31; if (cc >= nbgt) cc = nbgt - 1;
        bp[j] = fb + (size_t)bgidx[t * N + cc] * C + koff;
    }

    floatx16 acc[2][4];
    for (int i = 0; i < 2; ++i)
        for (int j = 0; j < 4; ++j)
            acc[i][j] = (floatx16)(0.f);

    bf16x8 afr[3][2], bfr[3][4];
    #pragma unroll
    for (int s = 0; s < 2; ++s) {
        for (int i = 0; i < 2; ++i) afr[s][i] = *(const bf16x8*)(ap[i] + s * 16);
        for (int j = 0; j < 4; ++j) bfr[s][j] = *(const bf16x8*)(bp[j] + s * 16);
    }

    #pragma unroll
    for (int kk = 0; kk < 16; ++kk) {          // K = 256, 16 per step
        int cur = kk % 3;
        int nxt = (kk + 2) % 3;
        if (kk + 2 < 16) {
            int off = (kk + 2) * 16;
            for (int i = 0; i < 2; ++i) afr[nxt][i] = *(const bf16x8*)(ap[i] + off);
            for (int j = 0; j < 4; ++j) bfr[nxt][j] = *(const bf16x8*)(bp[j] + off);
        }
        for (int i = 0; i < 2; ++i)
            for (int j = 0; j < 4; ++j)
                acc[i][j] = __builtin_amdgcn_mfma_f32_32x32x16_bf16(afr[cur][i], bfr[cur][j], acc[i][j], 0, 0, 0);
    }

    // epilogue: exp + bg-mask + row reduction.
    // C/D layout (32x32): col = lane&31, row = (reg&3) + 8*(reg>>2) + 4*(lane>>5)
    float bgv[4];
    for (int j = 0; j < 4; ++j)
        bgv[j] = (colbase + j * 32 + l31 < nbgt) ? 1.f : 0.f;

    int rquad = 4 * (lane >> 5);
    for (int i = 0; i < 2; ++i) {
        #pragma unroll
        for (int reg = 0; reg < 16; ++reg) {
            float msum = 0.f;
            for (int j = 0; j < 4; ++j)
                msum += __expf(acc[i][j][reg] * TEMP_INV) * bgv[j];
            msum += __shfl_xor(msum, 1);
            msum += __shfl_xor(msum, 2);
            msum += __shfl_xor(msum, 4);
            msum += __shfl_xor(msum, 8);
            msum += __shfl_xor(msum, 16);
            if (l31 == 0) {
                int row = rowbase + i * 32 + (reg & 3) + 8 * (reg >> 2) + rquad;
                if (row < nfgt) atomicAdd(&neg[t * N + row], msum);
            }
        }
    }
}

// ---------------------------------------------------------------------------
// Fused per-frame + final loss: 512 threads, wave t handles frame t.
__global__ void loss_kernel(const float* __restrict__ negbuf,
                            const float* __restrict__ posdot,
                            const unsigned short* __restrict__ fgidx,
                            const int* __restrict__ nfg,
                            const int* __restrict__ nbg,
                            float* __restrict__ out_loss) {
    int tid = threadIdx.x;
    int t = tid >> 6;
    int lane = tid & 63;
    int nfgt = nfg[t];
    float s = 0.f;
    for (int k = lane; k < nfgt; k += 64) {
        int pix = fgidx[t * N + k];
        float pos = __expf(posdot[t * N + pix] * TEMP_INV);
        float ng = negbuf[t * N + k];
        s += logf((pos + ng + EPS) / pos);
    }
    for (int o = 32; o > 0; o >>= 1) s += __shfl_down(s, o);
    __shared__ float fl[8], vv[8];
    if (lane == 0) {
        float valid = (nfgt > 0 && nbg[t] > 0) ? 1.f : 0.f;
        fl[t] = valid * (s / fmaxf((float)nfgt, 1.f));
        vv[t] = valid;
    }
    __syncthreads();
    if (tid == 0) {
        float ls = 0.f, v = 0.f;
        for (int i = 0; i < T; ++i) { ls += fl[i]; v += vv[i]; }
        out_loss[0] = (v > 0.f) ? ls / fmaxf(v, 1.f) : 0.f;
    }
}

// ---------------------------------------------------------------------------
extern "C" void kernel_launch(void* const* d_in, const int* in_sizes, int n_in,
                              void* d_out, int out_size, void* d_ws, size_t ws_size,
                              hipStream_t stream) {
    const float* cur  = (const float*)d_in[0];
    const float* hist = (const float*)d_in[1];
    const float* feat = (const float*)d_in[2];
    float* out = (float*)d_out;   // labels[32768] ++ loss[1]

    char* ws = (char*)d_ws;
    bf16*  fhat    = (bf16*)ws;                           // 16 MiB
    float* negbuf  = (float*)(ws + 16777216);             // 32768 f32 (compacted fg rows)
    float* posdot  = (float*)(ws + 16908288);             // 32768 f32
    unsigned short* fgidx = (unsigned short*)(ws + 17039360);  // 32768 u16
    unsigned short* bgidx = (unsigned short*)(ws + 17104896);  // 32768 u16
    int*   nfg     = (int*)(ws + 17170432);
    int*   nbg     = nfg + 8;

    prep_kernel<<<8, 1024, 0, stream>>>(cur, hist, out, negbuf, fgidx, bgidx, nfg, nbg);
    normalize_kernel<<<512, 256, 0, stream>>>(feat, fhat, posdot);
    sim_kernel<<<16384, 64, 0, stream>>>(fhat, fgidx, bgidx, nfg, nbg, negbuf);
    loss_kernel<<<1, 512, 0, stream>>>(negbuf, posdot, fgidx, nfg, nbg, out + 32768);
}

// Round 5
// 153.509 us; speedup vs baseline: 1.5295x; 1.5295x over previous
//
#include <hip/hip_runtime.h>
#include <hip/hip_bf16.h>
#include <cstdint>
#include <cstddef>

// Problem constants
constexpr int T = 8;
constexpr int C = 256;     // feature channels = GEMM K
constexpr int N = 4096;    // H*W pixels per frame
constexpr float TEMP_INV = 14.285714285714286f;  // 1/0.07
constexpr float EPS = 1e-8f;

typedef __bf16 bf16;
typedef __bf16 bf16x8 __attribute__((ext_vector_type(8)));
typedef float floatx4 __attribute__((ext_vector_type(4)));

// ---------------------------------------------------------------------------
// async global->LDS, 16B per lane, wave-uniform LDS base + lane*16
__device__ __forceinline__ void async_copy16(const bf16* g, bf16* l) {
    __builtin_amdgcn_global_load_lds((const __attribute__((address_space(1))) void*)g,
                                     (__attribute__((address_space(3))) void*)l,
                                     16, 0, 0);
}

// ---------------------------------------------------------------------------
// Fused per-frame dice stats + labels + negbuf zero + fg/bg compaction.
// Grid: 8 blocks (one per frame) x 1024 threads (16 waves).
__global__ void prep_kernel(const float* __restrict__ cur,
                            const float* __restrict__ hist,
                            float* __restrict__ out_labels,
                            float* __restrict__ negbuf,
                            unsigned short* __restrict__ fgidx,
                            unsigned short* __restrict__ bgidx,
                            int* __restrict__ nfg, int* __restrict__ nbg) {
    int t = blockIdx.x;
    int tid = threadIdx.x;
    int lane = tid & 63;
    int w = tid >> 6;

    float cv[4], hv[4];
    float s1 = 0.f, sc = 0.f, sh = 0.f;
    #pragma unroll
    for (int it = 0; it < 4; ++it) {
        int p = it * 1024 + tid;
        float c = cur[t * N + p];
        float h = hist[t * N + p];
        cv[it] = c; hv[it] = h;
        float cb = c > 0.5f ? 1.f : 0.f;
        float hb = h > 0.5f ? 1.f : 0.f;
        s1 += cb * hb; sc += cb; sh += hb;
    }
    for (int o = 32; o > 0; o >>= 1) {
        s1 += __shfl_down(s1, o);
        sc += __shfl_down(sc, o);
        sh += __shfl_down(sh, o);
    }
    __shared__ float r1[16], r2[16], r3[16];
    __shared__ float uflag;
    __shared__ int cfg_s, cbg_s;
    if (lane == 0) { r1[w] = s1; r2[w] = sc; r3[w] = sh; }
    if (tid == 0) { cfg_s = 0; cbg_s = 0; }
    __syncthreads();
    if (tid == 0) {
        float e1 = 0.f, scs = 0.f, shs = 0.f;
        for (int i = 0; i < 16; ++i) { e1 += r1[i]; scs += r2[i]; shs += r3[i]; }
        float e2 = scs + shs;
        float m1 = (2.f * e1 + EPS) / (e2 + EPS);
        float m2 = (e1 + EPS) / (e2 - e1 + EPS);
        float dev = 1.f - 0.5f * (m1 + m2);
        uflag = (dev <= 0.0f) ? 1.f : 0.f;
    }
    __syncthreads();
    bool use_curr = uflag != 0.f;
    for (int it = 0; it < 4; ++it) {
        int p = it * 1024 + tid;
        int gi = t * N + p;
        float lab = use_curr ? cv[it] : hv[it];
        out_labels[gi] = lab;
        negbuf[gi] = 0.f;
        bool fg = lab > 0.5f;
        unsigned long long b = __ballot(fg);
        unsigned long long lowmask = (lane == 63) ? 0x7fffffffffffffffull
                                                  : ((1ull << lane) - 1ull);
        int rank_fg = __popcll(b & lowmask);
        int rank_bg = __popcll((~b) & lowmask);
        int cnt_fg = __popcll(b);
        int base_fg = 0, base_bg = 0;
        if (lane == 0) {
            base_fg = atomicAdd(&cfg_s, cnt_fg);
            base_bg = atomicAdd(&cbg_s, 64 - cnt_fg);
        }
        base_fg = __shfl(base_fg, 0);
        base_bg = __shfl(base_bg, 0);
        if (fg) fgidx[t * N + base_fg + rank_fg] = (unsigned short)p;
        else    bgidx[t * N + base_bg + rank_bg] = (unsigned short)p;
    }
    __syncthreads();
    if (tid == 0) { nfg[t] = cfg_s; nbg[t] = cbg_s; }
}

// ---------------------------------------------------------------------------
// Normalize features, transpose [T][C][N] -> bf16 [T][N][C], posdot = ||fhat||^2.
// Load loop unrolled 16-deep so the strided global loads pipeline.
__global__ __launch_bounds__(256, 4) void normalize_kernel(const float* __restrict__ feat,
                                                           bf16* __restrict__ fhat,
                                                           float* __restrict__ posdot) {
    __shared__ bf16 tile[64 * 258];    // [n][c], pad 258 (bf16)
    __shared__ float partial[256];
    __shared__ float rnorm_s[64];
    int t = blockIdx.x >> 6;           // 8 frames
    int n0 = (blockIdx.x & 63) * 64;   // 64 pixel rows per block
    int tid = threadIdx.x;
    int lane63 = tid & 63;             // pixel within tile
    int w = tid >> 6;                  // wave -> 64-channel slab
    const float* fb = feat + (size_t)t * C * N;
    float ss = 0.f;
    #pragma unroll 16
    for (int it = 0; it < 64; ++it) {
        int c = w * 64 + it;
        float v = fb[(size_t)c * N + n0 + lane63];
        ss += v * v;
        tile[lane63 * 258 + c] = (bf16)v;
    }
    partial[tid] = ss;
    __syncthreads();
    if (tid < 64) {
        float s = partial[tid] + partial[tid + 64] + partial[tid + 128] + partial[tid + 192];
        float r = 1.f / fmaxf(sqrtf(s), 1e-12f);
        rnorm_s[tid] = r;
        posdot[t * N + n0 + tid] = s * r * r;
    }
    __syncthreads();
    bf16* ob = fhat + ((size_t)t * N + n0) * C;
    #pragma unroll
    for (int it = 0; it < 8; ++it) {
        int l = it * 256 + tid;        // short8 index, 0..2047
        int n = l >> 5;
        int c = (l & 31) * 8;
        float r = rnorm_s[n];
        bf16x8 vin = *(const bf16x8*)&tile[n * 258 + c];
        bf16x8 vo;
        for (int j = 0; j < 8; ++j) vo[j] = (bf16)((float)vin[j] * r);
        *(bf16x8*)(ob + l * 8) = vo;
    }
}

// ---------------------------------------------------------------------------
// Fused sim GEMM + exp + row reduction over COMPACTED fg rows x bg cols.
// R2 structure (proven best): 128x128 tile, 4 waves, single-buffer LDS staging
// via global_load_lds w16 + XOR-chunk swizzle. Round-5 deltas:
//  - 1D grid, frame = blockIdx & 7  -> frame-per-XCD pinning (L2-resident fhat)
//  - __launch_bounds__(256,3) -> 3 blocks/CU co-resident to overlap drains
__global__ __launch_bounds__(256, 3) void sim_kernel(const bf16* __restrict__ fhat,
                                                     const unsigned short* __restrict__ fgidx,
                                                     const unsigned short* __restrict__ bgidx,
                                                     const int* __restrict__ nfg,
                                                     const int* __restrict__ nbg,
                                                     float* __restrict__ neg) {
    int t = blockIdx.x & 7;            // frame -> XCD pin (8 XCDs)
    int tile = blockIdx.x >> 3;        // 0..1023
    int rowbase = (tile >> 5) * 128;
    int colbase = (tile & 31) * 128;
    int nfgt = nfg[t];
    int nbgt = nbg[t];
    if (rowbase >= nfgt || colbase >= nbgt) return;

    __shared__ bf16 a_lds[128 * 64];
    __shared__ bf16 b_lds[128 * 64];
    int tid = threadIdx.x;
    int lane = tid & 63;
    int w = tid >> 6;
    const bf16* fb = fhat + (size_t)t * N * C;

    int ch = (lane & 7) ^ (lane >> 3);   // swizzled global chunk this lane fetches
    int r0w = (w & 1) * 64;
    int c0w = (w >> 1) * 64;

    const bf16* arp[4];
    const bf16* brp[4];
    for (int s = 0; s < 4; ++s) {
        int q = w * 4 + s;
        int row_l = q * 8 + (lane >> 3);          // 0..127 local row
        int ra = rowbase + row_l; if (ra >= nfgt) ra = nfgt - 1;
        int rb = colbase + row_l; if (rb >= nbgt) rb = nbgt - 1;
        arp[s] = fb + (size_t)fgidx[t * N + ra] * C + ch * 8;
        brp[s] = fb + (size_t)bgidx[t * N + rb] * C + ch * 8;
    }

    floatx4 acc[4][4];
    for (int i = 0; i < 4; ++i)
        for (int j = 0; j < 4; ++j)
            acc[i][j] = (floatx4){0.f, 0.f, 0.f, 0.f};

    for (int ks = 0; ks < 4; ++ks) {
        int k0 = ks * 64;
        __syncthreads();
        for (int s = 0; s < 4; ++s) {
            int q = w * 4 + s;                 // 0..15
            async_copy16(arp[s] + k0, &a_lds[q * 512]);
            async_copy16(brp[s] + k0, &b_lds[q * 512]);
        }
        __syncthreads();
        for (int kk = 0; kk < 64; kk += 32) {
            int quad = lane >> 4;
            int chread = (kk >> 3) + quad;     // global chunk wanted (0..7)
            bf16x8 af[4], bfr[4];
            for (int i = 0; i < 4; ++i) {
                int r = r0w + 16 * i + (lane & 15);
                int chs = chread ^ (r & 7);
                af[i] = *(const bf16x8*)&a_lds[r * 64 + chs * 8];
            }
            for (int j = 0; j < 4; ++j) {
                int cidx = c0w + 16 * j + (lane & 15);
                int chs = chread ^ (cidx & 7);
                bfr[j] = *(const bf16x8*)&b_lds[cidx * 64 + chs * 8];
            }
            for (int i = 0; i < 4; ++i)
                for (int j = 0; j < 4; ++j)
                    acc[i][j] = __builtin_amdgcn_mfma_f32_16x16x32_bf16(af[i], bfr[j], acc[i][j], 0, 0, 0);
        }
    }

    // epilogue: exp + row-sum; mask padded cols, guard padded rows
    float bgv[4];
    for (int j = 0; j < 4; ++j) {
        int cidx = colbase + c0w + 16 * j + (lane & 15);
        bgv[j] = (cidx < nbgt) ? 1.f : 0.f;
    }

    int quad = lane >> 4;
    for (int i = 0; i < 4; ++i) {
        for (int reg = 0; reg < 4; ++reg) {
            float msum = 0.f;
            for (int j = 0; j < 4; ++j)
                msum += __expf(acc[i][j][reg] * TEMP_INV) * bgv[j];
            msum += __shfl_xor(msum, 1);
            msum += __shfl_xor(msum, 2);
            msum += __shfl_xor(msum, 4);
            msum += __shfl_xor(msum, 8);
            if ((lane & 15) == 0) {
                int row = rowbase + r0w + 16 * i + quad * 4 + reg;   // compacted fg row
                if (row < nfgt) atomicAdd(&neg[t * N + row], msum);
            }
        }
    }
}

// ---------------------------------------------------------------------------
// Fused per-frame + final loss: 512 threads, wave t handles frame t.
__global__ void loss_kernel(const float* __restrict__ negbuf,
                            const float* __restrict__ posdot,
                            const unsigned short* __restrict__ fgidx,
                            const int* __restrict__ nfg,
                            const int* __restrict__ nbg,
                            float* __restrict__ out_loss) {
    int tid = threadIdx.x;
    int t = tid >> 6;
    int lane = tid & 63;
    int nfgt = nfg[t];
    float s = 0.f;
    #pragma unroll 4
    for (int k = lane; k < nfgt; k += 64) {
        int pix = fgidx[t * N + k];
        float pos = __expf(posdot[t * N + pix] * TEMP_INV);
        float ng = negbuf[t * N + k];
        s += logf((pos + ng + EPS) / pos);
    }
    for (int o = 32; o > 0; o >>= 1) s += __shfl_down(s, o);
    __shared__ float fl[8], vv[8];
    if (lane == 0) {
        float valid = (nfgt > 0 && nbg[t] > 0) ? 1.f : 0.f;
        fl[t] = valid * (s / fmaxf((float)nfgt, 1.f));
        vv[t] = valid;
    }
    __syncthreads();
    if (tid == 0) {
        float ls = 0.f, v = 0.f;
        for (int i = 0; i < T; ++i) { ls += fl[i]; v += vv[i]; }
        out_loss[0] = (v > 0.f) ? ls / fmaxf(v, 1.f) : 0.f;
    }
}

// ---------------------------------------------------------------------------
extern "C" void kernel_launch(void* const* d_in, const int* in_sizes, int n_in,
                              void* d_out, int out_size, void* d_ws, size_t ws_size,
                              hipStream_t stream) {
    const float* cur  = (const float*)d_in[0];
    const float* hist = (const float*)d_in[1];
    const float* feat = (const float*)d_in[2];
    float* out = (float*)d_out;   // labels[32768] ++ loss[1]

    char* ws = (char*)d_ws;
    bf16*  fhat    = (bf16*)ws;                           // 16 MiB
    float* negbuf  = (float*)(ws + 16777216);             // 32768 f32 (compacted fg rows)
    float* posdot  = (float*)(ws + 16908288);             // 32768 f32
    unsigned short* fgidx = (unsigned short*)(ws + 17039360);  // 32768 u16
    unsigned short* bgidx = (unsigned short*)(ws + 17104896);  // 32768 u16
    int*   nfg     = (int*)(ws + 17170432);
    int*   nbg     = nfg + 8;

    prep_kernel<<<8, 1024, 0, stream>>>(cur, hist, out, negbuf, fgidx, bgidx, nfg, nbg);
    normalize_kernel<<<512, 256, 0, stream>>>(feat, fhat, posdot);
    sim_kernel<<<8192, 256, 0, stream>>>(fhat, fgidx, bgidx, nfg, nbg, negbuf);
    loss_kernel<<<1, 512, 0, stream>>>(negbuf, posdot, fgidx, nfg, nbg, out + 32768);
}

// Round 6
// 149.096 us; speedup vs baseline: 1.5748x; 1.0296x over previous
//
#include <hip/hip_runtime.h>
#include <hip/hip_bf16.h>
#include <cstdint>
#include <cstddef>

// Problem constants
constexpr int T = 8;
constexpr int C = 256;     // feature channels = GEMM K
constexpr int N = 4096;    // H*W pixels per frame
constexpr int CAP = 4232;  // packed rows per frame: >= roundup(nfg,8)+roundup(nbg,128), mult of 8
constexpr float TEMP_INV = 14.285714285714286f;  // 1/0.07
constexpr float EPS = 1e-8f;

typedef __bf16 bf16;
typedef __bf16 bf16x8 __attribute__((ext_vector_type(8)));
typedef float floatx4 __attribute__((ext_vector_type(4)));

// ---------------------------------------------------------------------------
// async global->LDS, 16B per lane, wave-uniform LDS base + lane*16
__device__ __forceinline__ void async_copy16(const bf16* g, bf16* l) {
    __builtin_amdgcn_global_load_lds((const __attribute__((address_space(1))) void*)g,
                                     (__attribute__((address_space(3))) void*)l,
                                     16, 0, 0);
}

// ---------------------------------------------------------------------------
// Fused per-frame dice stats + labels + negbuf zero + rank map + pad zeroing.
// Grid: 8 blocks (one per frame) x 1024 threads.
__global__ void prep_kernel(const float* __restrict__ cur,
                            const float* __restrict__ hist,
                            float* __restrict__ out_labels,
                            float* __restrict__ negbuf,
                            unsigned short* __restrict__ rankmap,
                            bf16* __restrict__ fpack,
                            int* __restrict__ nfg, int* __restrict__ nbg) {
    int t = blockIdx.x;
    int tid = threadIdx.x;
    int lane = tid & 63;
    int w = tid >> 6;

    float cv[4], hv[4];
    float s1 = 0.f, sc = 0.f, sh = 0.f;
    #pragma unroll
    for (int it = 0; it < 4; ++it) {
        int p = it * 1024 + tid;
        float c = cur[t * N + p];
        float h = hist[t * N + p];
        cv[it] = c; hv[it] = h;
        float cb = c > 0.5f ? 1.f : 0.f;
        float hb = h > 0.5f ? 1.f : 0.f;
        s1 += cb * hb; sc += cb; sh += hb;
    }
    for (int o = 32; o > 0; o >>= 1) {
        s1 += __shfl_down(s1, o);
        sc += __shfl_down(sc, o);
        sh += __shfl_down(sh, o);
    }
    __shared__ float r1[16], r2[16], r3[16];
    __shared__ float uflag;
    __shared__ int cfg_s, cbg_s;
    if (lane == 0) { r1[w] = s1; r2[w] = sc; r3[w] = sh; }
    if (tid == 0) { cfg_s = 0; cbg_s = 0; }
    __syncthreads();
    if (tid == 0) {
        float e1 = 0.f, scs = 0.f, shs = 0.f;
        for (int i = 0; i < 16; ++i) { e1 += r1[i]; scs += r2[i]; shs += r3[i]; }
        float e2 = scs + shs;
        float m1 = (2.f * e1 + EPS) / (e2 + EPS);
        float m2 = (e1 + EPS) / (e2 - e1 + EPS);
        float dev = 1.f - 0.5f * (m1 + m2);
        uflag = (dev <= 0.0f) ? 1.f : 0.f;
    }
    __syncthreads();
    bool use_curr = uflag != 0.f;
    for (int it = 0; it < 4; ++it) {
        int p = it * 1024 + tid;
        int gi = t * N + p;
        float lab = use_curr ? cv[it] : hv[it];
        out_labels[gi] = lab;
        negbuf[gi] = 0.f;
        bool fg = lab > 0.5f;
        unsigned long long b = __ballot(fg);
        unsigned long long lowmask = (lane == 63) ? 0x7fffffffffffffffull
                                                  : ((1ull << lane) - 1ull);
        int rank_fg = __popcll(b & lowmask);
        int rank_bg = __popcll((~b) & lowmask);
        int cnt_fg = __popcll(b);
        int base_fg = 0, base_bg = 0;
        if (lane == 0) {
            base_fg = atomicAdd(&cfg_s, cnt_fg);
            base_bg = atomicAdd(&cbg_s, 64 - cnt_fg);
        }
        base_fg = __shfl(base_fg, 0);
        base_bg = __shfl(base_bg, 0);
        int rank = fg ? (base_fg + rank_fg) : (base_bg + rank_bg);
        rankmap[gi] = (unsigned short)(rank | (fg ? 0x8000 : 0));
    }
    __syncthreads();
    if (tid == 0) { nfg[t] = cfg_s; nbg[t] = cbg_s; }
    // zero pad rows [N, CAP) of this frame's packed array (covers B-tile overreads)
    float4 z4 = make_float4(0.f, 0.f, 0.f, 0.f);
    float4* pz = (float4*)(fpack + ((size_t)t * CAP + N) * C);
    int chunks = (CAP - N) * (C / 8);          // 16B chunks
    for (int i = tid; i < chunks; i += 1024) pz[i] = z4;
}

// ---------------------------------------------------------------------------
// Normalize features, cast bf16, and SCATTER each pixel row to its compacted
// position in fpack (fg ranks first, bg ranks at roundup(nfg,8)), applying the
// XOR-chunk swizzle at the store so sim's staging reads are fully contiguous.
// Also writes posdot compacted by fg rank.
__global__ __launch_bounds__(256, 4) void normalize_kernel(const float* __restrict__ feat,
                                                           const unsigned short* __restrict__ rankmap,
                                                           const int* __restrict__ nfg,
                                                           bf16* __restrict__ fpack,
                                                           float* __restrict__ posc) {
    __shared__ bf16 tile[64 * 258];    // [n][c], true chunk order, pad 258
    __shared__ float partial[256];
    __shared__ float rnorm_s[64];
    __shared__ unsigned short rk_s[64];
    __shared__ int bbase_s;
    int t = blockIdx.x >> 6;           // 8 frames
    int n0 = (blockIdx.x & 63) * 64;   // 64 pixel rows per block
    int tid = threadIdx.x;
    int lane63 = tid & 63;             // pixel within tile
    int w = tid >> 6;                  // wave -> 64-channel slab
    if (tid == 0) bbase_s = (nfg[t] + 7) & ~7;
    if (tid < 64) rk_s[tid] = rankmap[t * N + n0 + tid];
    const float* fb = feat + (size_t)t * C * N;
    float ss = 0.f;
    #pragma unroll 16
    for (int it = 0; it < 64; ++it) {
        int c = w * 64 + it;
        float v = fb[(size_t)c * N + n0 + lane63];
        ss += v * v;
        tile[lane63 * 258 + c] = (bf16)v;
    }
    partial[tid] = ss;
    __syncthreads();
    if (tid < 64) {
        float s = partial[tid] + partial[tid + 64] + partial[tid + 128] + partial[tid + 192];
        float r = 1.f / fmaxf(sqrtf(s), 1e-12f);
        rnorm_s[tid] = r;
        unsigned short rk = rk_s[tid];
        if (rk & 0x8000) posc[t * N + (rk & 0x7fff)] = s * r * r;  // fg only
    }
    __syncthreads();
    int bbase = bbase_s;
    bf16* fp = fpack + (size_t)t * CAP * C;
    #pragma unroll
    for (int it = 0; it < 8; ++it) {
        int l = it * 256 + tid;        // short8 index, 0..2047
        int n = l >> 5;                // tile row (pixel)
        int c8 = l & 31;               // true 16B-chunk index 0..31
        unsigned short rk = rk_s[n];
        int r_pack = (rk & 0x7fff) + ((rk & 0x8000) ? 0 : bbase);
        int slot = (c8 & ~7) | ((c8 & 7) ^ (r_pack & 7));   // swizzled store pos
        float r = rnorm_s[n];
        bf16x8 vin = *(const bf16x8*)&tile[n * 258 + c8 * 8];
        bf16x8 vo;
        for (int j = 0; j < 8; ++j) vo[j] = (bf16)((float)vin[j] * r);
        *(bf16x8*)(fp + (size_t)r_pack * C + slot * 8) = vo;
    }
}

// ---------------------------------------------------------------------------
// Fused sim GEMM + exp + row reduction over compacted fg rows x bg cols.
// Staging is now FULLY CONTIGUOUS (m97 fast path): rows pre-compacted and
// pre-swizzled in fpack; LDS fragment reads stay conflict-free.
__global__ __launch_bounds__(256, 3) void sim_kernel(const bf16* __restrict__ fpack,
                                                     const int* __restrict__ nfg,
                                                     const int* __restrict__ nbg,
                                                     float* __restrict__ neg) {
    int t = blockIdx.x & 7;            // frame -> XCD pin (8 XCDs)
    int tile = blockIdx.x >> 3;        // 0..1023
    int rowbase = (tile >> 5) * 128;
    int colbase = (tile & 31) * 128;
    int nfgt = nfg[t];
    int nbgt = nbg[t];
    if (rowbase >= nfgt || colbase >= nbgt) return;
    int bbase = (nfgt + 7) & ~7;       // packed row where bg rows start

    __shared__ bf16 a_lds[128 * 64];
    __shared__ bf16 b_lds[128 * 64];
    int tid = threadIdx.x;
    int lane = tid & 63;
    int w = tid >> 6;
    const bf16* fb = fpack + (size_t)t * CAP * C;

    int lrow = lane >> 3;              // row within 8-row group
    int lchunk = lane & 7;             // 16B chunk within 128B subrow
    int r0w = (w & 1) * 64;
    int c0w = (w >> 1) * 64;

    floatx4 acc[4][4];
    for (int i = 0; i < 4; ++i)
        for (int j = 0; j < 4; ++j)
            acc[i][j] = (floatx4){0.f, 0.f, 0.f, 0.f};

    for (int ks = 0; ks < 4; ++ks) {
        int k0 = ks * 64;
        __syncthreads();
        for (int s = 0; s < 4; ++s) {
            int q = w * 4 + s;                 // 0..15
            int ra = rowbase + q * 8 + lrow;           // contiguous packed fg row
            int rb = bbase + colbase + q * 8 + lrow;   // contiguous packed bg row
            async_copy16(fb + (size_t)ra * C + k0 + lchunk * 8, &a_lds[q * 512]);
            async_copy16(fb + (size_t)rb * C + k0 + lchunk * 8, &b_lds[q * 512]);
        }
        __syncthreads();
        for (int kk = 0; kk < 64; kk += 32) {
            int quad = lane >> 4;
            int chread = (kk >> 3) + quad;     // wanted true chunk (0..7)
            bf16x8 af[4], bfr[4];
            for (int i = 0; i < 4; ++i) {
                int r = r0w + 16 * i + (lane & 15);
                int chs = chread ^ (r & 7);
                af[i] = *(const bf16x8*)&a_lds[r * 64 + chs * 8];
            }
            for (int j = 0; j < 4; ++j) {
                int cidx = c0w + 16 * j + (lane & 15);
                int chs = chread ^ (cidx & 7);
                bfr[j] = *(const bf16x8*)&b_lds[cidx * 64 + chs * 8];
            }
            for (int i = 0; i < 4; ++i)
                for (int j = 0; j < 4; ++j)
                    acc[i][j] = __builtin_amdgcn_mfma_f32_16x16x32_bf16(af[i], bfr[j], acc[i][j], 0, 0, 0);
        }
    }

    // epilogue: exp + row-sum; mask padded cols, guard padded rows
    float bgv[4];
    for (int j = 0; j < 4; ++j) {
        int cidx = colbase + c0w + 16 * j + (lane & 15);
        bgv[j] = (cidx < nbgt) ? 1.f : 0.f;
    }
    int quad = lane >> 4;
    for (int i = 0; i < 4; ++i) {
        for (int reg = 0; reg < 4; ++reg) {
            float msum = 0.f;
            for (int j = 0; j < 4; ++j)
                msum += __expf(acc[i][j][reg] * TEMP_INV) * bgv[j];
            msum += __shfl_xor(msum, 1);
            msum += __shfl_xor(msum, 2);
            msum += __shfl_xor(msum, 4);
            msum += __shfl_xor(msum, 8);
            if ((lane & 15) == 0) {
                int row = rowbase + r0w + 16 * i + quad * 4 + reg;   // compacted fg row
                if (row < nfgt) atomicAdd(&neg[t * N + row], msum);
            }
        }
    }
}

// ---------------------------------------------------------------------------
// Fused per-frame + final loss: 512 threads, wave t handles frame t.
// All reads contiguous (neg and pos both compacted by fg rank).
__global__ void loss_kernel(const float* __restrict__ negbuf,
                            const float* __restrict__ posc,
                            const int* __restrict__ nfg,
                            const int* __restrict__ nbg,
                            float* __restrict__ out_loss) {
    int tid = threadIdx.x;
    int t = tid >> 6;
    int lane = tid & 63;
    int nfgt = nfg[t];
    float s = 0.f;
    #pragma unroll 4
    for (int k = lane; k < nfgt; k += 64) {
        float pos = __expf(posc[t * N + k] * TEMP_INV);
        float ng = negbuf[t * N + k];
        s += logf((pos + ng + EPS) / pos);
    }
    for (int o = 32; o > 0; o >>= 1) s += __shfl_down(s, o);
    __shared__ float fl[8], vv[8];
    if (lane == 0) {
        float valid = (nfgt > 0 && nbg[t] > 0) ? 1.f : 0.f;
        fl[t] = valid * (s / fmaxf((float)nfgt, 1.f));
        vv[t] = valid;
    }
    __syncthreads();
    if (tid == 0) {
        float ls = 0.f, v = 0.f;
        for (int i = 0; i < T; ++i) { ls += fl[i]; v += vv[i]; }
        out_loss[0] = (v > 0.f) ? ls / fmaxf(v, 1.f) : 0.f;
    }
}

// ---------------------------------------------------------------------------
extern "C" void kernel_launch(void* const* d_in, const int* in_sizes, int n_in,
                              void* d_out, int out_size, void* d_ws, size_t ws_size,
                              hipStream_t stream) {
    const float* cur  = (const float*)d_in[0];
    const float* hist = (const float*)d_in[1];
    const float* feat = (const float*)d_in[2];
    float* out = (float*)d_out;   // labels[32768] ++ loss[1]

    char* ws = (char*)d_ws;
    bf16*  fpack   = (bf16*)ws;                           // T*CAP*C bf16 = 17.33 MB
    size_t off = (size_t)T * CAP * C * sizeof(bf16);      // 17334272
    float* negbuf  = (float*)(ws + off);  off += (size_t)T * N * 4;   // 131072
    float* posc    = (float*)(ws + off);  off += (size_t)T * N * 4;   // 131072
    unsigned short* rankmap = (unsigned short*)(ws + off); off += (size_t)T * N * 2;
    int*   nfg     = (int*)(ws + off);
    int*   nbg     = nfg + 8;

    prep_kernel<<<8, 1024, 0, stream>>>(cur, hist, out, negbuf, rankmap, fpack, nfg, nbg);
    normalize_kernel<<<512, 256, 0, stream>>>(feat, rankmap, nfg, fpack, posc);
    sim_kernel<<<8192, 256, 0, stream>>>(fpack, nfg, nbg, negbuf);
    loss_kernel<<<1, 512, 0, stream>>>(negbuf, posc, nfg, nbg, out + 32768);
}